// Round 4
// baseline (29991.278 us; speedup 1.0000x reference)
//
#include <hip/hip_runtime.h>

#define HSTEPS 8640
#define HID 128
#define BATCH 16
#define NTHR 1024
#define YRING 192

typedef _Float16 h16;
typedef __attribute__((ext_vector_type(2))) _Float16 h16x2;
typedef __attribute__((ext_vector_type(8))) _Float16 h16x8;

static __device__ __forceinline__ float fdot2f(h16x2 a, h16x2 b, float c) {
    return __builtin_amdgcn_fdot2(a, b, c, false);
}
static __device__ __forceinline__ float sigm(float x) {
    return __builtin_amdgcn_rcpf(1.0f + __expf(-x));
}
static __device__ __forceinline__ float tanh_f(float x) {
    float ax = __builtin_fabsf(x);
    float ee = __expf(2.0f * ax);
    float r = 1.0f - 2.0f * __builtin_amdgcn_rcpf(ee + 1.0f);
    return __builtin_copysignf(r, x);
}

template <int CTRL>
static __device__ __forceinline__ float dppmov(float x) {
    return __int_as_float(
        __builtin_amdgcn_mov_dpp(__float_as_int(x), CTRL, 0xF, 0xF, false));
}
// lane^4 exchange (stays inside the 8-lane element group)
static __device__ __forceinline__ float swz4(float x) {
    return __int_as_float(
        __builtin_amdgcn_ds_swizzle(__float_as_int(x), 0x101F));
}
// sum of 16-periodic values -> every lane holds the 16-group sum
static __device__ __forceinline__ float sum16(float x) {
    x += dppmov<0x121>(x);  // row_ror:1
    x += dppmov<0x122>(x);  // row_ror:2
    x += dppmov<0x124>(x);  // row_ror:4
    x += dppmov<0x128>(x);  // row_ror:8
    return x;
}
// full wave64 sum -> total lands in lane 63
static __device__ __forceinline__ float red_wave(float x) {
    x += dppmov<0x121>(x);
    x += dppmov<0x122>(x);
    x += dppmov<0x124>(x);
    x += dppmov<0x128>(x);
    float t1 = __int_as_float(__builtin_amdgcn_update_dpp(
        0, __float_as_int(x), 0x142 /*row_bcast15*/, 0xA, 0xF, false));
    x += t1;
    float t2 = __int_as_float(__builtin_amdgcn_update_dpp(
        0, __float_as_int(x), 0x143 /*row_bcast31*/, 0xC, 0xF, false));
    x += t2;
    return x;
}

// lane holds gate q; n1/n2/n3 are gate values from q^1/q^2/q^3.
// Same verified selection as round 3's quad_act.
static __device__ __forceinline__ float act4(float G, float n1, float n2,
                                             float n3, int q, float& c) {
    bool b0 = (q & 1) != 0, b1 = (q & 2) != 0;
    float gi = b1 ? (b0 ? n3 : n2) : (b0 ? n1 : G);
    float gf = b1 ? (b0 ? n2 : n3) : (b0 ? G : n1);
    float gg = b1 ? (b0 ? n1 : G) : (b0 ? n3 : n2);
    float go = b1 ? (b0 ? G : n1) : (b0 ? n2 : n3);
    float si = sigm(gi), sf = sigm(gf), so = sigm(go);
    float tg = tanh_f(gg);
    c = __builtin_fmaf(sf, c, si * tg);
    return so * tanh_f(c);
}

#define R8(F) F(0) F(1) F(2) F(3) F(4) F(5) F(6) F(7)

// One block per batch; 1024 threads = 16 waves (4/SIMD @ <=128 VGPR tier).
// Thread t: e = t>>3 (element), q = (t>>1)&3 (gate), half = t&1 (col half).
// Owns HALF-ROW (64 cols) of row 128q+e in Whh0, Wih1, Whh1 as 24 named
// h16x8 registers = 96 weight VGPRs. Half-partials combine via lane^1 DPP;
// gate gather via lane^2 DPP + lane^4 ds_swizzle; acts replicated in-register
// (c-state replicated x8). 2 barriers/step; y staged in LDS ring.
__global__ __launch_bounds__(NTHR, 4) void lstm2_kernel(
    const float* __restrict__ y0, const float* __restrict__ h0in,
    const float* __restrict__ c0in, const float* __restrict__ Wih0,
    const float* __restrict__ Whh0, const float* __restrict__ bih0,
    const float* __restrict__ bhh0, const float* __restrict__ Wih1,
    const float* __restrict__ Whh1, const float* __restrict__ bih1,
    const float* __restrict__ bhh1, const float* __restrict__ fcw,
    const float* __restrict__ fcb, float* __restrict__ out) {
    const int b = blockIdx.x;
    const int t = threadIdx.x;
    const int e = t >> 3;
    const int sub = t & 7;
    const int q = sub >> 1;
    const int half = t & 1;
    const int row = (q << 7) | e;
    const int half64 = half << 6;

    __shared__ __align__(16) h16 h0s[2][HID];
    __shared__ __align__(16) h16 h1s[2][HID];
    __shared__ float ypartbuf[16];
    __shared__ float ybuf[YRING];

#define DW(i) h16x8 w0_##i, w1_##i, w2_##i;
    R8(DW)

    {
        const float* rp = Whh0 + row * HID + half64;
#define LWA(i)                                                              \
    {                                                                       \
        float4 x_ = *(const float4*)(rp + i * 8);                           \
        float4 y_ = *(const float4*)(rp + i * 8 + 4);                       \
        w0_##i = h16x8{(h16)x_.x, (h16)x_.y, (h16)x_.z, (h16)x_.w,          \
                       (h16)y_.x, (h16)y_.y, (h16)y_.z, (h16)y_.w};         \
    }
        R8(LWA)
        rp = Wih1 + row * HID + half64;
#define LWB(i)                                                              \
    {                                                                       \
        float4 x_ = *(const float4*)(rp + i * 8);                           \
        float4 y_ = *(const float4*)(rp + i * 8 + 4);                       \
        w1_##i = h16x8{(h16)x_.x, (h16)x_.y, (h16)x_.z, (h16)x_.w,          \
                       (h16)y_.x, (h16)y_.y, (h16)y_.z, (h16)y_.w};         \
    }
        R8(LWB)
        rp = Whh1 + row * HID + half64;
#define LWC(i)                                                              \
    {                                                                       \
        float4 x_ = *(const float4*)(rp + i * 8);                           \
        float4 y_ = *(const float4*)(rp + i * 8 + 4);                       \
        w2_##i = h16x8{(h16)x_.x, (h16)x_.y, (h16)x_.z, (h16)x_.w,          \
                       (h16)y_.x, (h16)y_.y, (h16)y_.z, (h16)y_.w};         \
    }
        R8(LWC)
    }

    const float bias0t = bih0[row] + bhh0[row];
    const float bias1t = bih1[row] + bhh1[row];
    const float wih0t = Wih0[row];
    const float fcb_ = fcb[0];
    const float fcw_e = fcw[e];

    float c0 = c0in[b * HID + e];            // replicated x8
    float c1 = c0in[(BATCH + b) * HID + e];  // replicated x8

    if (sub == 0) {
        h0s[0][e] = (h16)h0in[b * HID + e];
        h1s[0][e] = (h16)h0in[(BATCH + b) * HID + e];
    }
    if (t < 16) ypartbuf[t] = (t == 0) ? (y0[b] - fcb_) : 0.0f;
    __syncthreads();

    float* outb = out + (size_t)b * HSTEPS;
    int p = 0;
    int ys = 0;
    int flush_at = YRING;

#pragma unroll 1
    for (int s = 0; s < HSTEPS; ++s) {
        // ---- y = fc output of previous step (every lane) ----
        float yv = sum16(ypartbuf[t & 15]) + fcb_;
        if (s > 0) {
            if (t == 0) ybuf[ys] = yv;
            ys = (ys == YRING - 1) ? 0 : ys + 1;
        }

        // ---- phase A: half-dots Whh0@h0_prev and Whh1@h1_prev ----
        const h16* h0p = &h0s[p][half64];
        const h16* h1p = &h1s[p][half64];
        float a0 = (half == 0) ? __builtin_fmaf(wih0t, yv, bias0t) : 0.0f;
        float a1 = 0.f, a2 = 0.f, a3 = 0.f;
        float u0 = 0.f, u1 = 0.f, u2 = 0.f, u3 = 0.f;
#define DA(i)                                                                  \
    {                                                                          \
        h16x8 hv = *(const h16x8*)(h0p + i * 8);                               \
        a0 = fdot2f(h16x2{w0_##i[0], w0_##i[1]}, h16x2{hv[0], hv[1]}, a0);     \
        a1 = fdot2f(h16x2{w0_##i[2], w0_##i[3]}, h16x2{hv[2], hv[3]}, a1);     \
        a2 = fdot2f(h16x2{w0_##i[4], w0_##i[5]}, h16x2{hv[4], hv[5]}, a2);     \
        a3 = fdot2f(h16x2{w0_##i[6], w0_##i[7]}, h16x2{hv[6], hv[7]}, a3);     \
    }
        R8(DA)
#define DU(i)                                                                  \
    {                                                                          \
        h16x8 hv = *(const h16x8*)(h1p + i * 8);                               \
        u0 = fdot2f(h16x2{w2_##i[0], w2_##i[1]}, h16x2{hv[0], hv[1]}, u0);     \
        u1 = fdot2f(h16x2{w2_##i[2], w2_##i[3]}, h16x2{hv[2], hv[3]}, u1);     \
        u2 = fdot2f(h16x2{w2_##i[4], w2_##i[5]}, h16x2{hv[4], hv[5]}, u2);     \
        u3 = fdot2f(h16x2{w2_##i[6], w2_##i[7]}, h16x2{hv[6], hv[7]}, u3);     \
    }
        R8(DU)
        float accA = (a0 + a1) + (a2 + a3);
        float g1half = (u0 + u1) + (u2 + u3);  // Whh1 half-partial, carried

        // combine halves (lane^1), gather gates (lane^2, lane^4), act0
        float G0 = accA + dppmov<0xB1>(accA);
        float n1 = dppmov<0x4E>(G0);
        float n2 = swz4(G0);
        float n3 = swz4(n1);
        float h0n = act4(G0, n1, n2, n3, q, c0);
        if (sub == 0) h0s[p ^ 1][e] = (h16)h0n;
        __syncthreads();  // B1: h0 new ready

        // ---- periodic output flush (uniform, 1/192 steps) ----
        if (s == flush_at) {
            if (t < YRING) outb[flush_at - YRING + t] = ybuf[t];
            flush_at += YRING;
        }

        // ---- phase B: half-dot Wih1@h0n, combine with Whh1 partial ----
        const h16* h0np = &h0s[p ^ 1][half64];
        float v0 = (half == 0) ? bias1t : 0.0f;
        float v1 = 0.f, v2 = 0.f, v3 = 0.f;
#define DB(i)                                                                  \
    {                                                                          \
        h16x8 hv = *(const h16x8*)(h0np + i * 8);                              \
        v0 = fdot2f(h16x2{w1_##i[0], w1_##i[1]}, h16x2{hv[0], hv[1]}, v0);     \
        v1 = fdot2f(h16x2{w1_##i[2], w1_##i[3]}, h16x2{hv[2], hv[3]}, v1);     \
        v2 = fdot2f(h16x2{w1_##i[4], w1_##i[5]}, h16x2{hv[4], hv[5]}, v2);     \
        v3 = fdot2f(h16x2{w1_##i[6], w1_##i[7]}, h16x2{hv[6], hv[7]}, v3);     \
    }
        R8(DB)
        float S = ((v0 + v1) + (v2 + v3)) + g1half;
        float G1 = S + dppmov<0xB1>(S);
        float m1 = dppmov<0x4E>(G1);
        float m2 = swz4(G1);
        float m3 = swz4(m1);
        float h1n = act4(G1, m1, m2, m3, q, c1);
        if (sub == 0) h1s[p ^ 1][e] = (h16)h1n;

        // ---- fused fc: one contribution per element, wave-reduce ----
        float part = (sub == 0) ? fcw_e * h1n : 0.0f;
        part = red_wave(part);
        if ((t & 63) == 63) ypartbuf[t >> 6] = part;

        p ^= 1;
        __syncthreads();  // B2: h1/ypart ready
    }

    // ---- tail: y(8639) + final flush ----
    float yv = sum16(ypartbuf[t & 15]) + fcb_;
    if (t == 0) ybuf[YRING - 1] = yv;
    __syncthreads();
    if (t < YRING) outb[HSTEPS - YRING + t] = ybuf[t];
}

extern "C" void kernel_launch(void* const* d_in, const int* in_sizes, int n_in,
                              void* d_out, int out_size, void* d_ws,
                              size_t ws_size, hipStream_t stream) {
    const float* y0 = (const float*)d_in[0];
    const float* h0 = (const float*)d_in[1];
    const float* c0 = (const float*)d_in[2];
    const float* Wih0 = (const float*)d_in[3];
    const float* Whh0 = (const float*)d_in[4];
    const float* bih0 = (const float*)d_in[5];
    const float* bhh0 = (const float*)d_in[6];
    const float* Wih1 = (const float*)d_in[7];
    const float* Whh1 = (const float*)d_in[8];
    const float* bih1 = (const float*)d_in[9];
    const float* bhh1 = (const float*)d_in[10];
    const float* fcw = (const float*)d_in[11];
    const float* fcb = (const float*)d_in[12];
    float* out = (float*)d_out;

    lstm2_kernel<<<dim3(BATCH), dim3(NTHR), 0, stream>>>(
        y0, h0, c0, Wih0, Whh0, bih0, bhh0, Wih1, Whh1, bih1, bhh1, fcw, fcb,
        out);
}

// Round 6
// 11186.996 us; speedup vs baseline: 2.6809x; 2.6809x over previous
//
#include <hip/hip_runtime.h>

#define HSTEPS 8640
#define HID 128
#define BATCH 16
#define NTHR 512
#define YRING 192

typedef _Float16 h16;
typedef __attribute__((ext_vector_type(8))) _Float16 h16x8;
typedef __attribute__((ext_vector_type(4))) float f32x4;

static __device__ __forceinline__ float sigm(float x) {
    return __builtin_amdgcn_rcpf(1.0f + __expf(-x));
}
static __device__ __forceinline__ float tanh_f(float x) {
    float ax = __builtin_fabsf(x);
    float ee = __expf(2.0f * ax);
    float r = 1.0f - 2.0f * __builtin_amdgcn_rcpf(ee + 1.0f);
    return __builtin_copysignf(r, x);
}
template <int CTRL>
static __device__ __forceinline__ float dppmov(float x) {
    return __int_as_float(
        __builtin_amdgcn_mov_dpp(__float_as_int(x), CTRL, 0xF, 0xF, false));
}
// sum of 8-periodic values across a 16-lane row -> every lane holds the sum
static __device__ __forceinline__ float sum8(float x) {
    x += dppmov<0x121>(x);
    x += dppmov<0x122>(x);
    x += dppmov<0x124>(x);
    return x;
}
// sum across each 16-lane row -> every lane holds its row's sum
static __device__ __forceinline__ float sum16(float x) {
    x += dppmov<0x121>(x);
    x += dppmov<0x122>(x);
    x += dppmov<0x124>(x);
    x += dppmov<0x128>(x);
    return x;
}

// ---- weight fragments: 48 named h16x8 (av-class: only read by MFMA) ----
#define FRAG_GC(F, m, g) F(m, g, 0) F(m, g, 1) F(m, g, 2) F(m, g, 3)
#define FRAG_M(F, m) FRAG_GC(F, m, 0) FRAG_GC(F, m, 1) FRAG_GC(F, m, 2) FRAG_GC(F, m, 3)
#define FRAG_ALL(F) FRAG_M(F, 0) FRAG_M(F, 1) FRAG_M(F, 2)

#define DECLF(m, g, c) h16x8 wf##m##_##g##_##c;

#define WPTR0 Whh0
#define WPTR1 Wih1
#define WPTR2 Whh1
// B[k][n]: lane l holds W[16*(wv+8g) + (l&15)][32c + 8*(l>>4) + j], j=0..7
#define LOADF(m, g, c)                                                         \
    {                                                                          \
        const float* p_ = WPTR##m +                                            \
            (size_t)((16 * (wv + 8 * g) + ln15) * HID + 32 * c + 8 * grp);     \
        float4 u_ = *(const float4*)p_;                                        \
        float4 v_ = *(const float4*)(p_ + 4);                                  \
        wf##m##_##g##_##c = h16x8{(h16)u_.x, (h16)u_.y, (h16)u_.z, (h16)u_.w,  \
                                  (h16)v_.x, (h16)v_.y, (h16)v_.z, (h16)v_.w}; \
    }

// D = A*B + C via intrinsic (compiler handles hazards + reg constraints)
#define MFMA(q, a, b) \
    q = __builtin_amdgcn_mfma_f32_16x16x32_f16((a), (b), (q), 0, 0, 0)

#define CHAIN(qv, m, g, r0, r1, r2, r3) \
    qv = zq;                            \
    MFMA(qv, r0, wf##m##_##g##_0);      \
    MFMA(qv, r1, wf##m##_##g##_1);      \
    MFMA(qv, r2, wf##m##_##g##_2);      \
    MFMA(qv, r3, wf##m##_##g##_3);
#define CHAIN_CONT(qv, m, g, r0, r1, r2, r3) \
    MFMA(qv, r0, wf##m##_##g##_0);           \
    MFMA(qv, r1, wf##m##_##g##_1);           \
    MFMA(qv, r2, wf##m##_##g##_2);           \
    MFMA(qv, r3, wf##m##_##g##_3);

// One block per batch; 512 threads = 8 waves, 2/SIMD (256 unified regs/thd).
// Weights: 192 regs/lane of MFMA-B fragments (AGPR-eligible). h broadcast
// from LDS as replicated A. Wave w owns gate tiles {w,w+8,w+16,w+24} ->
// lane l holds all 4 gates of element e = 16w + (l&15); act is in-lane.
__global__ __launch_bounds__(NTHR, 2) void lstm2_kernel(
    const float* __restrict__ y0, const float* __restrict__ h0in,
    const float* __restrict__ c0in, const float* __restrict__ Wih0,
    const float* __restrict__ Whh0, const float* __restrict__ bih0,
    const float* __restrict__ bhh0, const float* __restrict__ Wih1,
    const float* __restrict__ Whh1, const float* __restrict__ bih1,
    const float* __restrict__ bhh1, const float* __restrict__ fcw,
    const float* __restrict__ fcb, float* __restrict__ out) {
    const int b = blockIdx.x;
    const int t = threadIdx.x;
    const int wv = t >> 6;     // wave 0..7
    const int ln = t & 63;     // lane
    const int grp = ln >> 4;   // k-group 0..3
    const int ln15 = ln & 15;  // element-within-wave / B col
    const int ev = 16 * wv + ln15;  // this lane's element 0..127

    // hsm: [0..127]=h0 buf0, [128..255]=h0 buf1, [256..383]=h1 buf0, [384..511]=h1 buf1
    __shared__ __align__(16) h16 hsm[512];
    __shared__ float ypartbuf[8];
    __shared__ float ybuf[YRING];

    FRAG_ALL(DECLF)
    FRAG_ALL(LOADF)

    const float bias0_0 = bih0[ev] + bhh0[ev];
    const float bias0_1 = bih0[128 + ev] + bhh0[128 + ev];
    const float bias0_2 = bih0[256 + ev] + bhh0[256 + ev];
    const float bias0_3 = bih0[384 + ev] + bhh0[384 + ev];
    const float bias1_0 = bih1[ev] + bhh1[ev];
    const float bias1_1 = bih1[128 + ev] + bhh1[128 + ev];
    const float bias1_2 = bih1[256 + ev] + bhh1[256 + ev];
    const float bias1_3 = bih1[384 + ev] + bhh1[384 + ev];
    const float wih0_0 = Wih0[ev];
    const float wih0_1 = Wih0[128 + ev];
    const float wih0_2 = Wih0[256 + ev];
    const float wih0_3 = Wih0[384 + ev];
    const float fcb_ = fcb[0];
    const float fcw_e = fcw[ev];

    float c0v = c0in[b * HID + ev];            // replicated across k-groups
    float c1v = c0in[(BATCH + b) * HID + ev];  // replicated across k-groups

    if (ln < 16) {
        hsm[ev] = (h16)h0in[b * HID + ev];
        hsm[256 + ev] = (h16)h0in[(BATCH + b) * HID + ev];
    }
    if (t < 8) ypartbuf[t] = (t == 0) ? (y0[b] - fcb_) : 0.0f;
    __syncthreads();

    const f32x4 zq = {0.f, 0.f, 0.f, 0.f};
    float* outb = out + (size_t)b * HSTEPS;
    int p = 0;
    int ys = 0;
    int flush_at = YRING;

#pragma unroll 1
    for (int s = 0; s < HSTEPS; ++s) {
        // ---- y = fc output of previous step ----
        float yv = sum8(ypartbuf[ln & 7]) + fcb_;
        if (s > 0) {
            if (t == 0) ybuf[ys] = yv;
            ys = (ys == YRING - 1) ? 0 : ys + 1;
        }

        const int hp0 = 8 * grp + 128 * p;  // h0 buf p, this lane's slice

        // ---- phase A, part 1: q1 = Whh1 @ h1_prev (carried into phase B) ----
        h16x8 b0 = *(const h16x8*)&hsm[hp0 + 256];
        h16x8 b1 = *(const h16x8*)&hsm[hp0 + 288];
        h16x8 b2 = *(const h16x8*)&hsm[hp0 + 320];
        h16x8 b3 = *(const h16x8*)&hsm[hp0 + 352];
        f32x4 q1_0, q1_1, q1_2, q1_3;
        CHAIN(q1_0, 2, 0, b0, b1, b2, b3)
        CHAIN(q1_1, 2, 1, b0, b1, b2, b3)
        CHAIN(q1_2, 2, 2, b0, b1, b2, b3)
        CHAIN(q1_3, 2, 3, b0, b1, b2, b3)

        // ---- phase A, part 2: gates0 = Whh0 @ h0_prev + Wih0*y + bias0 ----
        h16x8 a0 = *(const h16x8*)&hsm[hp0];
        h16x8 a1 = *(const h16x8*)&hsm[hp0 + 32];
        h16x8 a2 = *(const h16x8*)&hsm[hp0 + 64];
        h16x8 a3 = *(const h16x8*)&hsm[hp0 + 96];
        f32x4 q0_0, q0_1, q0_2, q0_3;
        CHAIN(q0_0, 0, 0, a0, a1, a2, a3)
        CHAIN(q0_1, 0, 1, a0, a1, a2, a3)
        CHAIN(q0_2, 0, 2, a0, a1, a2, a3)
        CHAIN(q0_3, 0, 3, a0, a1, a2, a3)

        float G0 = q0_0[0] + __builtin_fmaf(wih0_0, yv, bias0_0);
        float G1 = q0_1[0] + __builtin_fmaf(wih0_1, yv, bias0_1);
        float G2 = q0_2[0] + __builtin_fmaf(wih0_2, yv, bias0_2);
        float G3 = q0_3[0] + __builtin_fmaf(wih0_3, yv, bias0_3);
        float si = sigm(G0), sf = sigm(G1), so = sigm(G3);
        float tg = tanh_f(G2);
        c0v = __builtin_fmaf(sf, c0v, si * tg);
        float h0nv = so * tanh_f(c0v);
        if (ln < 16) hsm[(p ^ 1) * 128 + ev] = (h16)h0nv;
        __syncthreads();  // B1: h0 new ready

        // ---- periodic output flush (uniform, 1/192 steps) ----
        if (s == flush_at) {
            if (t < YRING) outb[flush_at - YRING + t] = ybuf[t];
            flush_at += YRING;
        }

        // ---- phase B: q1 += Wih1 @ h0n ; act1 + fc ----
        const int hb = hp0 ^ 128;  // h0 buf p^1
        h16x8 d0 = *(const h16x8*)&hsm[hb];
        h16x8 d1 = *(const h16x8*)&hsm[hb + 32];
        h16x8 d2 = *(const h16x8*)&hsm[hb + 64];
        h16x8 d3 = *(const h16x8*)&hsm[hb + 96];
        CHAIN_CONT(q1_0, 1, 0, d0, d1, d2, d3)
        CHAIN_CONT(q1_1, 1, 1, d0, d1, d2, d3)
        CHAIN_CONT(q1_2, 1, 2, d0, d1, d2, d3)
        CHAIN_CONT(q1_3, 1, 3, d0, d1, d2, d3)

        float H0 = q1_0[0] + bias1_0;
        float H1 = q1_1[0] + bias1_1;
        float H2 = q1_2[0] + bias1_2;
        float H3 = q1_3[0] + bias1_3;
        float ti = sigm(H0), tf = sigm(H1), to = sigm(H3);
        float tgg = tanh_f(H2);
        c1v = __builtin_fmaf(tf, c1v, ti * tgg);
        float h1nv = to * tanh_f(c1v);
        if (ln < 16) hsm[256 + (p ^ 1) * 128 + ev] = (h16)h1nv;

        float part = sum16(fcw_e * h1nv);
        if (ln == 0) ypartbuf[wv] = part;

        p ^= 1;
        __syncthreads();  // B2: h1/ypart ready
    }

    // ---- tail: y(8639) + final flush ----
    float yv = sum8(ypartbuf[ln & 7]) + fcb_;
    if (t == 0) ybuf[YRING - 1] = yv;
    __syncthreads();
    if (t < YRING) outb[HSTEPS - YRING + t] = ybuf[t];
}

extern "C" void kernel_launch(void* const* d_in, const int* in_sizes, int n_in,
                              void* d_out, int out_size, void* d_ws,
                              size_t ws_size, hipStream_t stream) {
    const float* y0 = (const float*)d_in[0];
    const float* h0 = (const float*)d_in[1];
    const float* c0 = (const float*)d_in[2];
    const float* Wih0 = (const float*)d_in[3];
    const float* Whh0 = (const float*)d_in[4];
    const float* bih0 = (const float*)d_in[5];
    const float* bhh0 = (const float*)d_in[6];
    const float* Wih1 = (const float*)d_in[7];
    const float* Whh1 = (const float*)d_in[8];
    const float* bih1 = (const float*)d_in[9];
    const float* bhh1 = (const float*)d_in[10];
    const float* fcw = (const float*)d_in[11];
    const float* fcb = (const float*)d_in[12];
    float* out = (float*)d_out;

    lstm2_kernel<<<dim3(BATCH), dim3(NTHR), 0, stream>>>(
        y0, h0, c0, Wih0, Whh0, bih0, bhh0, Wih1, Whh1, bih1, bhh1, fcw, fcb,
        out);
}